// Round 19
// baseline (112.841 us; speedup 1.0000x reference)
//
#include <hip/hip_runtime.h>

// IDWT2D db4, periodized. Input x: [64][256][256][16] f32 (cA|cH|cV|cD x 4ch),
// output: [64][512][512][4] f32.
//
// R18 = R17 (barrier-free wave-private pipelines) + WAVE-LOCAL FENCE.
// R17 failed (absmax 8.5): removing __syncthreads left the same-wave LDS
// producer->consumer completely unfenced -> compiler hoisted reads past
// writes / no lgkm completion guarantee (rule-18 class hazard). Fix: at
// each former barrier point, a wave-local fence: sched_barrier(0) +
// s_waitcnt lgkmcnt(0) ("memory") + sched_barrier(0). One scalar instr per
// row-step; does NOT couple waves (no s_barrier) and does NOT drain vmcnt
// (prefetch stays in flight).
// Structure: each wave owns 16 j-rows x 16 col-pairs, private LDS
// intermediate [2 buf][2 parity][2 lo/hi][19 cols] f32x4 (2.4 KB/wave,
// 9.5 KB/block); 256-thread blocks, ~60 VGPR -> 8 blocks/CU = 32
// independent pipelines/CU. Pass1: lanes 0..37 = (col, half), paired dense
// 32B loads, 4-row register window, prefetch 1 ahead. Pass2: 64 lanes = 1
// output f4 (p=l>>5, ocf=l&31), dense stores (2x512B runs/instr).

#define N 256
#define RJ 16
#define WC 16         // col-pairs per wave
#define HC 19         // intermediate cols incl. x-halo

typedef float f32x4 __attribute__((ext_vector_type(4)));

// Wave-local LDS fence: orders ds_write -> ds_read within the wave without
// s_barrier (no inter-wave coupling) and without draining vmcnt.
#define WAVE_FENCE()                                      \
  do {                                                    \
    __builtin_amdgcn_sched_barrier(0);                    \
    asm volatile("s_waitcnt lgkmcnt(0)" ::: "memory");    \
    __builtin_amdgcn_sched_barrier(0);                    \
  } while (0)

__device__ __forceinline__ f32x4 fma4v(const f32x4 acc, const float s,
                                       const f32x4 a) {
  const f32x4 sv = {s, s, s, s};
  return __builtin_elementwise_fma(a, sv, acc);
}

__global__ __launch_bounds__(256, 4) void idwt2_sep18_kernel(
    const float* __restrict__ x, float* __restrict__ out) {
  constexpr float LO[8] = {
      0.23037781330885523f,  0.7148465705525415f,  0.6308807679295904f,
      -0.02798376941698385f, -0.18703481171888114f, 0.030841381835986965f,
      0.032883011666982945f, -0.010597401784997278f};
  constexpr float HIW[8] = {
      -0.010597401784997278f, -0.032883011666982945f, 0.030841381835986965f,
      0.18703481171888114f,  -0.02798376941698385f,  -0.6308807679295904f,
      0.7148465705525415f,   -0.23037781330885523f};
  const float Lw[2][4] = {{LO[6], LO[4], LO[2], LO[0]},
                          {LO[7], LO[5], LO[3], LO[1]}};
  const float Hw[2][4] = {{HIW[6], HIW[4], HIW[2], HIW[0]},
                          {HIW[7], HIW[5], HIW[3], HIW[1]}};

  // [wave][buf][parity][lo/hi][col] f32x4 = 9728 B
  __shared__ f32x4 I[4][2][2][2][HC];

  const int t = threadIdx.x;
  const int w = t >> 6;
  const int l = t & 63;
  const int bx = blockIdx.x;
  // bx = b*64 + rowgroup*4 + colblock (block covers 64 col-pairs; wave w
  // owns col-pairs [colblock*64 + w*16, +16))
  const int cgb = bx & 3;
  const int rg = (bx >> 2) & 15;
  const int b = bx >> 6;
  const int r0 = rg * RJ;
  const int jc0 = cgb * 64 + w * WC;

  const f32x4* xb4 = reinterpret_cast<const f32x4*>(x) + (size_t)b * N * N * 4;
  f32x4* ob = reinterpret_cast<f32x4*>(out) + (size_t)b * (2 * N) * (2 * N);

  // ---- Pass1 identity: lanes 0..2*HC-1 = (col c_=l>>1, half sh=l&1) ----
  const bool doP1 = l < 2 * HC;
  const int c_ = l >> 1;
  const int sh = l & 1;  // 0: lo from (cA,cH); 1: hi from (cV,cD)
  const int scol = (jc0 + c_) & (N - 1);
  const f32x4* xcolp = xb4 + (size_t)scol * 4 + sh * 2;

  f32x4 wA[4], wB[4], nA, nB;
  auto ldrow = [&](int lr, f32x4& A, f32x4& B) {
    const int gr = (r0 + lr) & (N - 1);
    const f32x4* p = xcolp + (size_t)gr * (N * 4);
    A = p[0];
    B = p[1];
  };

  // y-filter local j-row j into I[w][buf]; window slot (j+sy)&3 = row j+sy.
  auto p1 = [&](int j, int buf) {
    f32x4 v0 = {0.f, 0.f, 0.f, 0.f};
    f32x4 v1 = {0.f, 0.f, 0.f, 0.f};
#pragma unroll
    for (int sy = 0; sy < 4; ++sy) {
      const f32x4 a = wA[(j + sy) & 3];
      const f32x4 bb = wB[(j + sy) & 3];
      v0 = fma4v(v0, Lw[0][sy], a);
      v0 = fma4v(v0, Hw[0][sy], bb);
      v1 = fma4v(v1, Lw[1][sy], a);
      v1 = fma4v(v1, Hw[1][sy], bb);
    }
    I[w][buf][0][sh][c_] = v0;
    I[w][buf][1][sh][c_] = v1;
  };

  // Prologue: window rows 0..3, prefetch row 4; p1(0) -> buf 0.
  if (doP1) {
#pragma unroll
    for (int m = 0; m < 4; ++m) ldrow(m, wA[m], wB[m]);
    ldrow(4, nA, nB);
    p1(0, 0);
    wA[0] = nA;  // row 4 -> slot 0 (row 0 dead)
    wB[0] = nB;
    ldrow(5, nA, nB);
  }
  WAVE_FENCE();

  // ---- Pass2 identity: p = l>>5, ocf = l&31 -> jx = ocf>>1, q = ocf&1 ----
  const int pp = l >> 5;
  const int ocf = l & 31;
  const int jx = ocf >> 1;
  const int q = ocf & 1;
  float Lq[4], Hq[4];
#pragma unroll
  for (int s = 0; s < 4; ++s) {
    Lq[s] = q ? Lw[1][s] : Lw[0][s];
    Hq[s] = q ? Hw[1][s] : Hw[0][s];
  }

#pragma unroll
  for (int c = 0; c < RJ; ++c) {
    const int buf = c & 1;

    // ---- Pass2: one output f4: row 2(r0+c)+pp, col f4 2*jc0+ocf ----
    f32x4 o = {0.f, 0.f, 0.f, 0.f};
#pragma unroll
    for (int s = 0; s < 4; ++s) {
      o = fma4v(o, Lq[s], I[w][buf][pp][0][jx + s]);
      o = fma4v(o, Hq[s], I[w][buf][pp][1][jx + s]);
    }
    const int jy = r0 + c;
    ob[(size_t)(2 * jy + pp) * (2 * N) + 2 * jc0 + ocf] = o;

    if (c < RJ - 1) {
      // ---- Pass1: j-row c+1 into other buffer (wave-private) ----
      if (doP1) {
        p1(c + 1, buf ^ 1);
        // Slide prefetched row c+5 -> slot (c+1)&3; issue row c+6.
        if (c <= RJ - 3) {
          wA[(c + 1) & 3] = nA;
          wB[(c + 1) & 3] = nB;
        }
        if (c <= RJ - 4) ldrow(c + 6, nA, nB);
      }
      // Order this step's ds_writes before next step's ds_reads.
      WAVE_FENCE();
    }
  }
}

extern "C" void kernel_launch(void* const* d_in, const int* in_sizes, int n_in,
                              void* d_out, int out_size, void* d_ws,
                              size_t ws_size, hipStream_t stream) {
  const float* x = reinterpret_cast<const float*>(d_in[0]);
  float* out = reinterpret_cast<float*>(d_out);
  const int grid = 64 * (N / RJ) * 4;  // 4096 blocks, 4 wave-tiles each
  idwt2_sep18_kernel<<<grid, 256, 0, stream>>>(x, out);
}

// Round 20
// 107.146 us; speedup vs baseline: 1.0532x; 1.0532x over previous
//
#include <hip/hip_runtime.h>

// IDWT2D db4, periodized. Input x: [64][256][256][16] f32 (cA|cH|cV|cD x 4ch),
// output: [64][512][512][4] f32.
//
// R19 = R14 verbatim (session best, 106.9 us) — revert from the R15-R18
// exploration arc. Structure: dense pass1 loads via lane-pair partial
// exchange: thread t owns input f4 j=t and j=t+512 (pixel p=t>>2, subband
// f=t&3) -> wave global loads are lane-contiguous 16 B. y-filter: thread
// computes both-parity partials with its family weights, swaps the
// opposite-parity partial with lane t^1 (__shfl_xor), adds, writes one f4
// per column to LDS plane f (0=lo*p0, 1=lo*p1, 2=hi*p0, 3=hi*p1).
// LDS I[2][4][258] f32x4 double-buffered. Pass2: thread = output column
// (dense f4 stores), 16 ds_read_b128 per row-step. 1-row chunks,
// lgkm-only barrier (no vmcnt drain), 4 blocks/CU.

#define N 256
#define RJ 16

typedef float f32x4 __attribute__((ext_vector_type(4)));

// lgkm-only barrier: LDS producer-consumer sync without vmcnt drain.
#define LGKM_BARRIER()                                   \
  do {                                                   \
    asm volatile("s_waitcnt lgkmcnt(0)" ::: "memory");   \
    __builtin_amdgcn_s_barrier();                        \
    asm volatile("" ::: "memory");                       \
  } while (0)

__device__ __forceinline__ f32x4 fma4v(const f32x4 acc, const float s,
                                       const f32x4 a) {
  const f32x4 sv = {s, s, s, s};
  return __builtin_elementwise_fma(a, sv, acc);
}

__device__ __forceinline__ f32x4 shflxor1(const f32x4 v) {
  f32x4 r;
  r.x = __shfl_xor(v.x, 1);
  r.y = __shfl_xor(v.y, 1);
  r.z = __shfl_xor(v.z, 1);
  r.w = __shfl_xor(v.w, 1);
  return r;
}

__global__ __launch_bounds__(512, 4) void idwt2_sep19_kernel(
    const float* __restrict__ x, float* __restrict__ out) {
  constexpr float LO[8] = {
      0.23037781330885523f,  0.7148465705525415f,  0.6308807679295904f,
      -0.02798376941698385f, -0.18703481171888114f, 0.030841381835986965f,
      0.032883011666982945f, -0.010597401784997278f};
  constexpr float HIW[8] = {
      -0.010597401784997278f, -0.032883011666982945f, 0.030841381835986965f,
      0.18703481171888114f,  -0.02798376941698385f,  -0.6308807679295904f,
      0.7148465705525415f,   -0.23037781330885523f};
  const float Lw[2][4] = {{LO[6], LO[4], LO[2], LO[0]},
                          {LO[7], LO[5], LO[3], LO[1]}};
  const float Hw[2][4] = {{HIW[6], HIW[4], HIW[2], HIW[0]},
                          {HIW[7], HIW[5], HIW[3], HIW[1]}};

  // [buf][plane][pixel] f32x4, pixel dim padded 256->258 for bank spread.
  __shared__ f32x4 I[2][4][258];

  const int t = threadIdx.x;
  const int bx = blockIdx.x;
  const int b = bx >> 4;           // 16 consecutive blocks per batch
  const int r0 = (bx & 15) * RJ;

  const f32x4* xb = reinterpret_cast<const f32x4*>(x) + (size_t)b * N * N * 4;
  f32x4* ob = reinterpret_cast<f32x4*>(out) + (size_t)b * (2 * N) * (2 * N);

  // ---- Pass1 identity: f4 index j = t (pixel p, subband-f4 f) + j+512 ----
  const int f = t & 3;
  const int p = t >> 2;  // 0..127; second column is p+128
  const bool fo = f & 1; // false: cA/cV (Lw family), true: cH/cD (Hw family)

  float w_own[4], w_opp[4];  // own-parity / opposite-parity weights
#pragma unroll
  for (int s = 0; s < 4; ++s) {
    w_own[s] = fo ? Hw[1][s] : Lw[0][s];
    w_opp[s] = fo ? Hw[0][s] : Lw[1][s];
  }

  f32x4 w0[4], w1[4], n0, n1;  // sliding windows for columns j=t, j=t+512
  auto ldrow = [&](int lr, f32x4& A, f32x4& B) {
    const int gr = (r0 + lr) & (N - 1);
    const f32x4* xrow = xb + (size_t)gr * (N * 4);
    A = xrow[t];
    B = xrow[t + 512];
  };

  // y-filter local j-row j into I[buf]; window slot (j+sy)&3 holds row j+sy.
  auto p1 = [&](int j, int buf) {
    f32x4 sAo = {0.f, 0.f, 0.f, 0.f}, sAx = {0.f, 0.f, 0.f, 0.f};
    f32x4 sBo = {0.f, 0.f, 0.f, 0.f}, sBx = {0.f, 0.f, 0.f, 0.f};
#pragma unroll
    for (int sy = 0; sy < 4; ++sy) {
      const f32x4 a = w0[(j + sy) & 3];
      const f32x4 bb = w1[(j + sy) & 3];
      sAo = fma4v(sAo, w_own[sy], a);
      sAx = fma4v(sAx, w_opp[sy], a);
      sBo = fma4v(sBo, w_own[sy], bb);
      sBx = fma4v(sBx, w_opp[sy], bb);
    }
    // Exchange opposite-parity partials with lane t^1, add to own.
    const f32x4 vA = sAo + shflxor1(sAx);
    const f32x4 vB = sBo + shflxor1(sBx);
    I[buf][f][p] = vA;
    I[buf][f][p + 128] = vB;
  };

  // Prologue: window rows 0..3, prefetch row 4; p1(0) -> I[0].
#pragma unroll
  for (int m = 0; m < 4; ++m) ldrow(m, w0[m], w1[m]);
  ldrow(4, n0, n1);
  p1(0, 0);
  w0[0] = n0;  // row 4 -> slot 0 (row 0 dead)
  w1[0] = n1;
  ldrow(5, n0, n1);
  LGKM_BARRIER();

  // ---- Pass2 identity: output column t (dense stores) ----
  const int jx = t >> 1;
  const int q = t & 1;
  float Lq[4], Hq[4];
#pragma unroll
  for (int s = 0; s < 4; ++s) {
    Lq[s] = q ? Lw[1][s] : Lw[0][s];
    Hq[s] = q ? Hw[1][s] : Hw[0][s];
  }

#pragma unroll
  for (int c = 0; c < RJ; ++c) {
    const int buf = c & 1;

    // ---- Pass2: x-filter j-row c from I[buf] ----
    // plane 0 = par0*lo, 1 = par1*lo, 2 = par0*hi, 3 = par1*hi
    f32x4 o0 = {0.f, 0.f, 0.f, 0.f};
    f32x4 o1 = {0.f, 0.f, 0.f, 0.f};
#pragma unroll
    for (int s = 0; s < 4; ++s) {
      const int xc = (jx + s) & (N - 1);
      o0 = fma4v(o0, Lq[s], I[buf][0][xc]);
      o0 = fma4v(o0, Hq[s], I[buf][2][xc]);
      o1 = fma4v(o1, Lq[s], I[buf][1][xc]);
      o1 = fma4v(o1, Hq[s], I[buf][3][xc]);
    }
    const int jy = r0 + c;
    f32x4* po = ob + (size_t)(2 * jy) * (2 * N) + t;
    po[0] = o0;
    po[2 * N] = o1;

    if (c < RJ - 1) {
      // ---- Pass1: j-row c+1 (uses window rows c+1..c+4) ----
      p1(c + 1, buf ^ 1);
      // Slide: row c+5 (prefetched, vmcnt-waited here) -> slot (c+1)&3;
      // issue prefetch of row c+6 (stays in flight across the barrier).
      if (c <= RJ - 3) {
        w0[(c + 1) & 3] = n0;
        w1[(c + 1) & 3] = n1;
      }
      if (c <= RJ - 4) ldrow(c + 6, n0, n1);
      LGKM_BARRIER();
    }
  }
}

extern "C" void kernel_launch(void* const* d_in, const int* in_sizes, int n_in,
                              void* d_out, int out_size, void* d_ws,
                              size_t ws_size, hipStream_t stream) {
  const float* x = reinterpret_cast<const float*>(d_in[0]);
  float* out = reinterpret_cast<float*>(d_out);
  const int grid = 64 * (N / RJ);  // 1024 blocks = 4 per CU
  idwt2_sep19_kernel<<<grid, 512, 0, stream>>>(x, out);
}